// Round 15
// baseline (176.559 us; speedup 1.0000x reference)
//
#include <hip/hip_runtime.h>
#include <hip/hip_bf16.h>

#define B_ 8
#define N_ 256
#define IN_ 256
#define OUT_ 256
#define H_ 4
#define HD_ 64
#define ALPHA_ 0.2f
#define EPS_ 1e-5f

#define S_ (B_*H_*N_*HD_)   // 524288

// ws layout (float* base ws):
//   ei_f   f32   [ws + 0,    S_)          [B][H][N][64]  (+be1)
//   si_f   f32   [ws + S_,  2S_)          [B][H][N][64]  (+ba1)
//   ej_b   bf16  at ws+2S_   (S_ ushorts) [B][H][N][64]
//   Wh_b   bf16  ej_b+S_     (S_ ushorts)
//   conc_b bf16  ws+3S_ +524288 (524288)
//   wfull  bf16  at ws+4S_   (262144)   [4 heads x {Wh|ei|ej|si}][256 f]
//   wo_t   bf16  wfull+262144 (65536)   [o][f]
//   bw_b   bf16  wo_t+65536   (32768)   [h][e][k: We|Wb]

typedef unsigned short ushort_t;
typedef __attribute__((ext_vector_type(8))) short short8;
typedef __attribute__((ext_vector_type(4))) float floatx4;

__device__ __forceinline__ float lrelu(float x) { return fmaxf(x, ALPHA_ * x); }
__device__ __forceinline__ ushort_t f2b(float x) {   // RNE f32->bf16
    unsigned u = __float_as_uint(x);
    unsigned r = ((u >> 16) & 1u) + 0x7fffu;
    return (ushort_t)((u + r) >> 16);
}
__device__ __forceinline__ unsigned pk2(float x0, float x1) {  // 2xf32 -> packed bf16x2 (RNE)
    __hip_bfloat162 p = __float22bfloat162_rn(make_float2(x0, x1));
    return *(unsigned*)&p;
}

// ---------------------------------------------------------------------------
// build: 84 blocks (weight tiles only — h_b staging deleted, prep2 reads f32 h).
//  blk<48 : wfull plain tiles (hh, cq, ft) via LDS transpose
//  <64    : W@Wa tiles (hh, ft), both operands in LDS
//  <80    : wo_t transpose tiles
//  else   : bw_b per head
// ---------------------------------------------------------------------------
__global__ __launch_bounds__(256) void build_kernel(
    const float* __restrict__ W, const float* __restrict__ We1,
    const float* __restrict__ Wa1, const float* __restrict__ Wo,
    ushort_t* __restrict__ wfull, ushort_t* __restrict__ wo_t,
    ushort_t* __restrict__ bw_b)
{
    const int blk = blockIdx.x;
    const int tid = threadIdx.x;
    const int r4 = tid >> 6, cl = tid & 63;

    if (blk < 48) {
        const int hh = blk / 12, rem = blk % 12;
        const int cq = rem >> 2, ft = rem & 3;
        const int f0 = ft * 64;
        __shared__ float tl[64][65];
        for (int r = r4; r < 64; r += 4) {
            float v;
            if (cq == 0)      v = W  [((size_t)hh * 256 + f0 + r) * 64 + cl];
            else if (cq == 1) v = We1[((size_t)hh * 512 + f0 + r) * 64 + cl];
            else              v = We1[((size_t)hh * 512 + 256 + f0 + r) * 64 + cl];
            tl[r][cl] = v;
        }
        __syncthreads();
        for (int cr = r4; cr < 64; cr += 4)
            wfull[((size_t)hh * 256 + cq * 64 + cr) * 256 + f0 + cl] = f2b(tl[cl][cr]);
    } else if (blk < 64) {
        const int mm = blk - 48;
        const int hh = mm >> 2, ft = mm & 3;
        const int f0 = ft * 64;
        __shared__ float wlds[64][65];   // [f][g]
        __shared__ float wa_l[64][65];   // [g][e]
        __shared__ float tl[64][65];     // [f][e]
        for (int r = r4; r < 64; r += 4) {
            wlds[r][cl] = W[((size_t)hh * 256 + f0 + r) * 64 + cl];
            wa_l[r][cl] = Wa1[((size_t)hh * 192 + r) * 64 + cl];
        }
        __syncthreads();
        for (int f = r4; f < 64; f += 4) {    // e = cl
            float acc = 0.f;
            #pragma unroll 8
            for (int g = 0; g < 64; ++g) acc += wlds[f][g] * wa_l[g][cl];
            tl[f][cl] = acc;
        }
        __syncthreads();
        for (int cr = r4; cr < 64; cr += 4)
            wfull[((size_t)hh * 256 + 192 + cr) * 256 + f0 + cl] = f2b(tl[cl][cr]);
    } else if (blk < 80) {
        const int bb = blk - 64;
        const int to = bb & 3, tf = bb >> 2;
        __shared__ float t[64][65];
        for (int rr = r4; rr < 64; rr += 4)
            t[rr][cl] = Wo[(size_t)(tf * 64 + rr) * 256 + to * 64 + cl];
        __syncthreads();
        for (int rr = r4; rr < 64; rr += 4)
            wo_t[(size_t)(to * 64 + rr) * 256 + tf * 64 + cl] = f2b(t[cl][rr]);
    } else {
        const int hh = blk - 80;
        for (int idx = tid; idx < 64 * 128; idx += 256) {
            const int e = idx >> 7, k = idx & 127;
            const int row = (k < 64) ? (128 + k) : k;
            bw_b[hh * 8192 + idx] = f2b(Wa1[(size_t)hh * 192 * 64 + row * 64 + e]);
        }
    }
}

// ---------------------------------------------------------------------------
// prep2: C[2048][1024] = bf16(h) @ wfull^T. A-frags packed in-register from
// f32 h (no h_b staging kernel). grid 1024: gm=blk&127 (M=16), gn=blk>>7.
// Epilogue scatters to Wh_b/ei_f/ej_b/si_f (no WhT).
// ---------------------------------------------------------------------------
__global__ __launch_bounds__(256) void prep2_kernel(
    const float* __restrict__ h, const ushort_t* __restrict__ wfull,
    const float* __restrict__ be1, const float* __restrict__ ba1,
    float* __restrict__ ws)
{
    const int gm = blockIdx.x & 127, gn = blockIdx.x >> 7;
    const int tid = threadIdx.x, lane = tid & 63, wid = tid >> 6;
    const int quad = lane >> 4, l15 = lane & 15;

    float*    ei_f = ws;
    float*    si_f = ws + S_;
    ushort_t* ej_b = (ushort_t*)(ws + 2 * (size_t)S_);
    ushort_t* Wh_b = ej_b + S_;

    floatx4 acc[2];
    #pragma unroll
    for (int nt = 0; nt < 2; ++nt) acc[nt] = (floatx4){0.f,0.f,0.f,0.f};

    #pragma unroll 2
    for (int ks = 0; ks < 8; ++ks) {
        const float* hp0 = &h[(size_t)(gm * 16 + l15) * 256 + ks * 32 + quad * 8];
        float4 a0 = *(const float4*)hp0;
        float4 a1 = *(const float4*)(hp0 + 4);
        union { unsigned u[4]; short8 s; } aw;
        aw.u[0] = pk2(a0.x, a0.y); aw.u[1] = pk2(a0.z, a0.w);
        aw.u[2] = pk2(a1.x, a1.y); aw.u[3] = pk2(a1.z, a1.w);
        #pragma unroll
        for (int nt = 0; nt < 2; ++nt) {
            short8 bfr = *(const short8*)&wfull[(size_t)(gn * 128 + wid * 32 + nt * 16 + l15) * 256 + ks * 32 + quad * 8];
            acc[nt] = __builtin_amdgcn_mfma_f32_16x16x32_bf16(aw.s, bfr, acc[nt], 0, 0, 0);
        }
    }

    #pragma unroll
    for (int nt = 0; nt < 2; ++nt) {
        const int colg = gn * 128 + wid * 32 + nt * 16 + l15;
        const int head = colg >> 8, c = colg & 255, type = c >> 6, d = c & 63;
        #pragma unroll
        for (int reg = 0; reg < 4; ++reg) {
            const int row = gm * 16 + quad * 4 + reg;
            const int b = row >> 8, n = row & 255;
            const size_t idx = ((size_t)(b * H_ + head) * 256 + n) * 64 + d;
            const float v = acc[nt][reg];
            if      (type == 0) Wh_b[idx] = f2b(v);
            else if (type == 1) ei_f[idx] = v + be1[head * 64 + d];
            else if (type == 2) ej_b[idx] = f2b(v);
            else                si_f[idx] = v + ba1[head * 64 + d];
        }
    }
}

// ---------------------------------------------------------------------------
// attn (R13-proven): transposed GEMM, barrier-free i-loop, wave-local softmax.
// grid 512, 2 blocks/CU (unified VGPR+AGPR ~256/wave caps at 2 waves/SIMD;
// R8 showed forcing 4 spills persistent regs -> 520 MB scratch).
// hp GEMM uses the per-lane Wh gather (R7-proven; WhT removed to cut prep2's
// transpose scatter — measured within 0.7us of the WhT path).
// ---------------------------------------------------------------------------
__global__ __launch_bounds__(256, 2) void attn_kernel(
    const int* __restrict__ adj, const float* __restrict__ wa2,
    const float* __restrict__ ba2, const float* __restrict__ ln_g,
    const float* __restrict__ ln_b, float* __restrict__ ws)
{
    const int blk  = blockIdx.x;
    const int ig   = blk & 15;
    const int head = (blk >> 4) & 3;
    const int b    = blk >> 6;
    const int i0   = ig * 16;
    const int tid  = threadIdx.x;
    const int lane = tid & 63;
    const int wid  = tid >> 6;
    const int quad = lane >> 4;
    const int l15  = lane & 15;
    const int bh   = b * H_ + head;

    __shared__ float    P_s[16 * 256];
    __shared__ ushort_t Pb_s[16 * 264];
    __shared__ float    ei_s[16 * 64];
    __shared__ float    si_s[16 * 64];
    __shared__ unsigned long long adjm_s[16 * 4];
    __shared__ float    hp_s[16 * 68];

    const float*    ei_f = ws;
    const float*    si_f = ws + S_;
    const ushort_t* ej_b = (const ushort_t*)(ws + 2 * (size_t)S_);
    const ushort_t* Wh_b = ej_b + S_;
    ushort_t*       conc = (ushort_t*)(ws + 3 * (size_t)S_) + 524288;
    const ushort_t* bw_b = (const ushort_t*)(ws + 4 * (size_t)S_) + 262144 + 65536;

    {
        const int ii = tid >> 4, c = tid & 15;
        *(float4*)&ei_s[ii * 64 + c * 4] =
            *(const float4*)&ei_f[((size_t)(bh * 256 + i0 + ii)) * 64 + c * 4];
        *(float4*)&si_s[ii * 64 + c * 4] =
            *(const float4*)&si_f[((size_t)(bh * 256 + i0 + ii)) * 64 + c * 4];
    }
    {
        int av[16];
        #pragma unroll
        for (int r = 0; r < 16; ++r)
            av[r] = adj[((size_t)(b * 256 + i0 + r)) * 256 + tid];
        #pragma unroll
        for (int r = 0; r < 16; ++r) {
            unsigned long long mk = __ballot(av[r] != 0);
            if (lane == 0) adjm_s[r * 4 + wid] = mk;
        }
    }

    // ---- persistent per-wave registers (i-invariant) ----
    uint4   ejr[4][2];     // raw ej pairs, j = wid*64 + nt*16 + l15   [nt][ks]
    short8  afrWe[4][2];   // We A-frags, e = mt*16 + l15              [mt][ks]
    floatx4 sjaccT[4][4];  // sj^T[e][j]                               [mt][nt]
    float   w6[4][4], w4[4][4];  // 0.6*wa2[e], 0.4*wa2[e]
    #pragma unroll
    for (int nt = 0; nt < 4; ++nt) {
        const size_t jrow = (size_t)(bh * 256 + wid * 64 + nt * 16 + l15) * 64;
        #pragma unroll
        for (int kk = 0; kk < 2; ++kk)
            ejr[nt][kk] = *(const uint4*)&ej_b[jrow + kk * 32 + quad * 8];
    }
    #pragma unroll
    for (int mt = 0; mt < 4; ++mt) {
        #pragma unroll
        for (int ks = 0; ks < 2; ++ks)
            afrWe[mt][ks] = *(const short8*)&bw_b[head * 8192 + (mt * 16 + l15) * 128 + ks * 32 + quad * 8];
        float4 wvv = *(const float4*)&wa2[head * 64 + mt * 16 + quad * 4];
        w6[mt][0] = 0.6f * wvv.x; w4[mt][0] = 0.4f * wvv.x;
        w6[mt][1] = 0.6f * wvv.y; w4[mt][1] = 0.4f * wvv.y;
        w6[mt][2] = 0.6f * wvv.z; w4[mt][2] = 0.4f * wvv.z;
        w6[mt][3] = 0.6f * wvv.w; w4[mt][3] = 0.4f * wvv.w;
    }
    {
        #pragma unroll
        for (int mt = 0; mt < 4; ++mt)
            #pragma unroll
            for (int nt = 0; nt < 4; ++nt) sjaccT[mt][nt] = (floatx4){0.f,0.f,0.f,0.f};
        #pragma unroll
        for (int ks = 2; ks < 4; ++ks) {
            short8 aWb[4], bWh[4];
            #pragma unroll
            for (int mt = 0; mt < 4; ++mt)
                aWb[mt] = *(const short8*)&bw_b[head * 8192 + (mt * 16 + l15) * 128 + ks * 32 + quad * 8];
            #pragma unroll
            for (int nt = 0; nt < 4; ++nt)
                bWh[nt] = *(const short8*)&Wh_b[((size_t)(bh * 256 + wid * 64 + nt * 16 + l15)) * 64
                                                + (ks - 2) * 32 + quad * 8];
            #pragma unroll
            for (int mt = 0; mt < 4; ++mt)
                #pragma unroll
                for (int nt = 0; nt < 4; ++nt)
                    sjaccT[mt][nt] = __builtin_amdgcn_mfma_f32_16x16x32_bf16(
                        aWb[mt], bWh[nt], sjaccT[mt][nt], 0, 0, 0);
        }
    }
    const float ba2h = ba2[head];

    __syncthreads();

    // ==== barrier-free loop over 16 queries ====
    for (int i = 0; i < 16; ++i) {
        floatx4 acc[4][4];
        #pragma unroll
        for (int ks = 0; ks < 2; ++ks) {
            short8 tfr[4];
            float ev[8];
            *(float4*)&ev[0] = *(const float4*)&ei_s[i * 64 + ks * 32 + quad * 8];
            *(float4*)&ev[4] = *(const float4*)&ei_s[i * 64 + ks * 32 + quad * 8 + 4];
            #pragma unroll
            for (int nt = 0; nt < 4; ++nt) {
                const unsigned* rw = (const unsigned*)&ejr[nt][ks];
                union { unsigned u[4]; short8 s; } ow;
                #pragma unroll
                for (int p = 0; p < 4; ++p) {
                    float x0 = __uint_as_float(rw[p] << 16)         + ev[2 * p];
                    float x1 = __uint_as_float(rw[p] & 0xffff0000u) + ev[2 * p + 1];
                    ow.u[p] = pk2(lrelu(x0), lrelu(x1));
                }
                tfr[nt] = ow.s;
            }
            if (ks == 0) {
                #pragma unroll
                for (int mt = 0; mt < 4; ++mt)
                    #pragma unroll
                    for (int nt = 0; nt < 4; ++nt)
                        acc[mt][nt] = __builtin_amdgcn_mfma_f32_16x16x32_bf16(
                            afrWe[mt][0], tfr[nt], sjaccT[mt][nt], 0, 0, 0);
            } else {
                #pragma unroll
                for (int mt = 0; mt < 4; ++mt)
                    #pragma unroll
                    for (int nt = 0; nt < 4; ++nt)
                        acc[mt][nt] = __builtin_amdgcn_mfma_f32_16x16x32_bf16(
                            afrWe[mt][1], tfr[nt], acc[mt][nt], 0, 0, 0);
            }
        }

        // epilogue: logit[j] = sum_e lrelu(q^T[e][j]+si[e])*wa2[e] + ba2
        float sv[4][4];
        #pragma unroll
        for (int mt = 0; mt < 4; ++mt)
            *(float4*)&sv[mt][0] = *(const float4*)&si_s[i * 64 + mt * 16 + quad * 4];
        #pragma unroll
        for (int nt = 0; nt < 4; ++nt) {
            float val = 0.f;
            #pragma unroll
            for (int mt = 0; mt < 4; ++mt)
                #pragma unroll
                for (int reg = 0; reg < 4; ++reg) {
                    const float t = acc[mt][nt][reg] + sv[mt][reg];
                    val = fmaf(t, w6[mt][reg], val);
                    val = fmaf(fabsf(t), w4[mt][reg], val);
                }
            val += __shfl_xor(val, 16, 64);
            val += __shfl_xor(val, 32, 64);
            if (quad == 0)
                P_s[i * 256 + wid * 64 + nt * 16 + l15] = val + ba2h;
        }
    }
    __syncthreads();   // all logits published

    // ==== wave-local masked softmax: wave wid owns rows wid, wid+4, +8, +12 ====
    #pragma unroll
    for (int rr = 0; rr < 4; ++rr) {
        const int r = rr * 4 + wid;
        float4 v = *(const float4*)&P_s[r * 256 + lane * 4];
        const unsigned mk = (unsigned)(adjm_s[r * 4 + quad] >> (l15 * 4)) & 0xFu;
        float v0 = (mk & 1u) ? v.x : -1e9f;
        float v1 = (mk & 2u) ? v.y : -1e9f;
        float v2 = (mk & 4u) ? v.z : -1e9f;
        float v3 = (mk & 8u) ? v.w : -1e9f;
        float m = fmaxf(fmaxf(v0, v1), fmaxf(v2, v3));
        #pragma unroll
        for (int off = 32; off >= 1; off >>= 1) m = fmaxf(m, __shfl_xor(m, off, 64));
        float p0 = __expf(v0 - m), p1 = __expf(v1 - m);
        float p2 = __expf(v2 - m), p3 = __expf(v3 - m);
        float s = (p0 + p1) + (p2 + p3);
        #pragma unroll
        for (int off = 32; off >= 1; off >>= 1) s += __shfl_xor(s, off, 64);
        const float inv = 1.f / s;
        uint2 o; o.x = pk2(p0 * inv, p1 * inv); o.y = pk2(p2 * inv, p3 * inv);
        *(uint2*)&Pb_s[r * 264 + lane * 4] = o;
    }
    __syncthreads();   // Pb complete

    // ==== hp GEMM: M=16 (i), N=64 (d=wid*16+l15), K=256 (j); Wh gather ====
    floatx4 hacc = (floatx4){0.f,0.f,0.f,0.f};
    #pragma unroll
    for (int s = 0; s < 8; ++s) {
        short8 af = *(const short8*)&Pb_s[l15 * 264 + s * 32 + quad * 8];
        short8 bf;
        #pragma unroll
        for (int jj = 0; jj < 8; ++jj)
            bf[jj] = (short)Wh_b[((size_t)(bh * 256) + s * 32 + quad * 8 + jj) * 64 + wid * 16 + l15];
        hacc = __builtin_amdgcn_mfma_f32_16x16x32_bf16(af, bf, hacc, 0, 0, 0);
    }
    #pragma unroll
    for (int reg = 0; reg < 4; ++reg)
        hp_s[(quad * 4 + reg) * 68 + wid * 16 + l15] = hacc[reg];
    __syncthreads();

    // ==== per-row LN over 64 d -> conc (bf16) ====
    const float gg = ln_g[head * 64 + lane];
    const float bb = ln_b[head * 64 + lane];
    #pragma unroll
    for (int pss = 0; pss < 4; ++pss) {
        const int r = pss * 4 + wid;
        const float v = hp_s[r * 68 + lane];
        float s1 = v, s2 = v * v;
        #pragma unroll
        for (int off = 32; off >= 1; off >>= 1) {
            s1 += __shfl_xor(s1, off, 64);
            s2 += __shfl_xor(s2, off, 64);
        }
        const float mean = s1 * (1.f / 64.f);
        const float var = s2 * (1.f / 64.f) - mean * mean;
        const float o = (v - mean) * __frsqrt_rn(var + EPS_) * gg + bb;
        conc[((size_t)(b * 256 + i0 + r)) * 256 + head * 64 + lane] = f2b(o);
    }
}

// ---------------------------------------------------------------------------
// out2: grid 256 (8 rows/block). A rows 8-15 duplicate 0-7; quad>=2 lanes
// skip LN/stores (avoids OOB h reads past row 2047).
// ---------------------------------------------------------------------------
__global__ __launch_bounds__(256) void out2_kernel(
    const float* __restrict__ h, const float* __restrict__ bo,
    const float* __restrict__ ln2_g, const float* __restrict__ ln2_b,
    const ushort_t* __restrict__ conc, const ushort_t* __restrict__ wo_t,
    float* __restrict__ out)
{
    const int rowbase = blockIdx.x * 8;
    const int tid = threadIdx.x, lane = tid & 63, wid = tid >> 6;
    const int quad = lane >> 4, l15 = lane & 15;

    __shared__ float s1a[8][4], s2a[8][4];

    floatx4 acc[4];
    #pragma unroll
    for (int nt = 0; nt < 4; ++nt) acc[nt] = (floatx4){0.f,0.f,0.f,0.f};

    #pragma unroll 2
    for (int ks = 0; ks < 8; ++ks) {
        short8 afr = *(const short8*)&conc[(size_t)(rowbase + (l15 & 7)) * 256 + ks * 32 + quad * 8];
        #pragma unroll
        for (int nt = 0; nt < 4; ++nt) {
            short8 bfr = *(const short8*)&wo_t[(size_t)(wid * 64 + nt * 16 + l15) * 256 + ks * 32 + quad * 8];
            acc[nt] = __builtin_amdgcn_mfma_f32_16x16x32_bf16(afr, bfr, acc[nt], 0, 0, 0);
        }
    }

    float x[4][4];
    if (quad < 2) {
        float s1[4], s2[4];
        #pragma unroll
        for (int reg = 0; reg < 4; ++reg) { s1[reg] = 0.f; s2[reg] = 0.f; }
        #pragma unroll
        for (int nt = 0; nt < 4; ++nt) {
            const int col = wid * 64 + nt * 16 + l15;
            const float bv = bo[col];
            #pragma unroll
            for (int reg = 0; reg < 4; ++reg) {
                const int row = rowbase + quad * 4 + reg;
                float v = acc[nt][reg] + bv + h[(size_t)row * 256 + col];
                x[nt][reg] = v;
                s1[reg] += v;
                s2[reg] += v * v;
            }
        }
        #pragma unroll
        for (int reg = 0; reg < 4; ++reg) {
            #pragma unroll
            for (int off = 1; off <= 8; off <<= 1) {
                s1[reg] += __shfl_xor(s1[reg], off, 64);
                s2[reg] += __shfl_xor(s2[reg], off, 64);
            }
            if (l15 == 0) {
                s1a[quad * 4 + reg][wid] = s1[reg];
                s2a[quad * 4 + reg][wid] = s2[reg];
            }
        }
    }
    __syncthreads();

    if (quad < 2) {
        #pragma unroll
        for (int reg = 0; reg < 4; ++reg) {
            const int r = quad * 4 + reg;
            const float S1 = s1a[r][0] + s1a[r][1] + s1a[r][2] + s1a[r][3];
            const float S2 = s2a[r][0] + s2a[r][1] + s2a[r][2] + s2a[r][3];
            const float mean = S1 * (1.f / 256.f);
            const float var = S2 * (1.f / 256.f) - mean * mean;
            const float rs = __frsqrt_rn(var + EPS_);
            const int row = rowbase + r;
            #pragma unroll
            for (int nt = 0; nt < 4; ++nt) {
                const int col = wid * 64 + nt * 16 + l15;
                out[(size_t)row * 256 + col] =
                    (x[nt][reg] - mean) * rs * ln2_g[col] + ln2_b[col];
            }
        }
    }
}

// ---------------------------------------------------------------------------
extern "C" void kernel_launch(void* const* d_in, const int* in_sizes, int n_in,
                              void* d_out, int out_size, void* d_ws, size_t ws_size,
                              hipStream_t stream)
{
    const float* h    = (const float*)d_in[0];
    const int*   adj  = (const int*)  d_in[1];
    const float* W    = (const float*)d_in[2];
    const float* We1  = (const float*)d_in[3];
    const float* be1  = (const float*)d_in[4];
    const float* Wa1  = (const float*)d_in[5];
    const float* ba1  = (const float*)d_in[6];
    const float* wa2  = (const float*)d_in[7];
    const float* ba2  = (const float*)d_in[8];
    const float* ln_g = (const float*)d_in[9];
    const float* ln_b = (const float*)d_in[10];
    const float* Wo   = (const float*)d_in[11];
    const float* bo   = (const float*)d_in[12];
    const float* ln2g = (const float*)d_in[13];
    const float* ln2b = (const float*)d_in[14];

    float* ws = (float*)d_ws;
    ushort_t* conc  = (ushort_t*)(ws + 3 * (size_t)S_) + 524288;
    ushort_t* wfull = (ushort_t*)(ws + 4 * (size_t)S_);
    ushort_t* wo_t  = wfull + 262144;
    ushort_t* bw_b  = wo_t + 65536;
    float* out = (float*)d_out;

    build_kernel<<<84,   256, 0, stream>>>(W, We1, Wa1, Wo, wfull, wo_t, bw_b);
    prep2_kernel<<<1024, 256, 0, stream>>>(h, wfull, be1, ba1, ws);
    attn_kernel <<<512,  256, 0, stream>>>(adj, wa2, ba2, ln_g, ln_b, ws);
    out2_kernel <<<256,  256, 0, stream>>>(h, bo, ln2g, ln2b, conc, wo_t, out);
}

// Round 16
// 154.098 us; speedup vs baseline: 1.1458x; 1.1458x over previous
//
#include <hip/hip_runtime.h>
#include <hip/hip_bf16.h>

#define B_ 8
#define N_ 256
#define IN_ 256
#define OUT_ 256
#define H_ 4
#define HD_ 64
#define ALPHA_ 0.2f
#define EPS_ 1e-5f

#define S_ (B_*H_*N_*HD_)   // 524288

// ws layout (float* base ws):
//   ei_f   f32   [ws + 0,  S_)            [B][H][N][64]  (+be1)
//   ej_b   bf16  at ws+S_   (S_ ushorts)  [B][H][N][64]
//   Wh_b   bf16  ej_b+S_    (S_ ushorts)
//   conc_b bf16  at ws+2S_  (524288)
// (wfull / wo_t / bw_b / si_f all deleted — weights gathered directly)

typedef unsigned short ushort_t;
typedef __attribute__((ext_vector_type(8))) short short8;
typedef __attribute__((ext_vector_type(4))) float floatx4;

__device__ __forceinline__ float lrelu(float x) { return fmaxf(x, ALPHA_ * x); }
__device__ __forceinline__ ushort_t f2b(float x) {   // RNE f32->bf16
    unsigned u = __float_as_uint(x);
    unsigned r = ((u >> 16) & 1u) + 0x7fffu;
    return (ushort_t)((u + r) >> 16);
}
__device__ __forceinline__ unsigned pk2(float x0, float x1) {  // 2xf32 -> packed bf16x2 (RNE)
    __hip_bfloat162 p = __float22bfloat162_rn(make_float2(x0, x1));
    return *(unsigned*)&p;
}
// gather 8 f32 at stride STRIDE, round to bf16 fragment
template<int STRIDE>
__device__ __forceinline__ short8 gcol(const float* __restrict__ base) {
    union { unsigned u[4]; short8 s; } w;
    #pragma unroll
    for (int p = 0; p < 4; ++p)
        w.u[p] = pk2(base[(2 * p) * STRIDE], base[(2 * p + 1) * STRIDE]);
    return w.s;
}

// ---------------------------------------------------------------------------
// prep2: C[2048 rows][768 cols] = bf16(h) @ B^T, B-frags gathered directly
// from f32 W / We1 (stride-64 columns, coalesced across l15 lanes).
// cols per head: {Wh(64) | ei(64) | ej(64)}. grid 768: gm=blk&127 (M=16),
// gn=blk>>7 in [0,6). Epilogue scatters Wh_b / ei_f / ej_b.
// ---------------------------------------------------------------------------
__global__ __launch_bounds__(256) void prep2_kernel(
    const float* __restrict__ h, const float* __restrict__ W,
    const float* __restrict__ We1, const float* __restrict__ be1,
    float* __restrict__ ws)
{
    const int gm = blockIdx.x & 127, gn = blockIdx.x >> 7;
    const int tid = threadIdx.x, lane = tid & 63, wid = tid >> 6;
    const int quad = lane >> 4, l15 = lane & 15;

    float*    ei_f = ws;
    ushort_t* ej_b = (ushort_t*)(ws + S_);
    ushort_t* Wh_b = ej_b + S_;

    // per-nt column identity + weight base (element [k=0][d])
    int headA[2], typeA[2], dA[2];
    const float* wbase[2];
    #pragma unroll
    for (int nt = 0; nt < 2; ++nt) {
        const int colg = gn * 128 + wid * 32 + nt * 16 + l15;   // [0,768)
        const int head = colg / 192;
        const int c    = colg - head * 192;
        const int type = c >> 6, d = c & 63;
        headA[nt] = head; typeA[nt] = type; dA[nt] = d;
        if (type == 0)      wbase[nt] = W   + (size_t)head * 16384 + d;
        else if (type == 1) wbase[nt] = We1 + (size_t)head * 32768 + d;
        else                wbase[nt] = We1 + (size_t)head * 32768 + 16384 + d;
    }

    floatx4 acc[2];
    #pragma unroll
    for (int nt = 0; nt < 2; ++nt) acc[nt] = (floatx4){0.f,0.f,0.f,0.f};

    #pragma unroll 2
    for (int ks = 0; ks < 8; ++ks) {
        const float* hp0 = &h[(size_t)(gm * 16 + l15) * 256 + ks * 32 + quad * 8];
        float4 a0 = *(const float4*)hp0;
        float4 a1 = *(const float4*)(hp0 + 4);
        union { unsigned u[4]; short8 s; } aw;
        aw.u[0] = pk2(a0.x, a0.y); aw.u[1] = pk2(a0.z, a0.w);
        aw.u[2] = pk2(a1.x, a1.y); aw.u[3] = pk2(a1.z, a1.w);
        #pragma unroll
        for (int nt = 0; nt < 2; ++nt) {
            short8 bfr = gcol<64>(wbase[nt] + (size_t)(ks * 32 + quad * 8) * 64);
            acc[nt] = __builtin_amdgcn_mfma_f32_16x16x32_bf16(aw.s, bfr, acc[nt], 0, 0, 0);
        }
    }

    #pragma unroll
    for (int nt = 0; nt < 2; ++nt) {
        const int head = headA[nt], type = typeA[nt], d = dA[nt];
        #pragma unroll
        for (int reg = 0; reg < 4; ++reg) {
            const int row = gm * 16 + quad * 4 + reg;
            const int b = row >> 8, n = row & 255;
            const size_t idx = ((size_t)(b * H_ + head) * 256 + n) * 64 + d;
            const float v = acc[nt][reg];
            if      (type == 0) Wh_b[idx] = f2b(v);
            else if (type == 1) ei_f[idx] = v + be1[head * 64 + d];
            else                ej_b[idx] = f2b(v);
        }
    }
}

// ---------------------------------------------------------------------------
// attn (R13-proven core): transposed GEMM, barrier-free i-loop, wave-local
// softmax. grid 512, 2 blocks/CU (unified VGPR+AGPR ~256/wave caps at
// 2 waves/SIMD; R8 showed forcing 4 spills -> 520 MB scratch).
// New: si computed in-block (si = Wh_b @ Wa + ba1, one MFMA pair/wave);
// We/Wb fragments gathered directly from f32 Wa1 (bw_b deleted).
// ---------------------------------------------------------------------------
__global__ __launch_bounds__(256, 2) void attn_kernel(
    const int* __restrict__ adj, const float* __restrict__ Wa1,
    const float* __restrict__ ba1, const float* __restrict__ wa2,
    const float* __restrict__ ba2, const float* __restrict__ ln_g,
    const float* __restrict__ ln_b, float* __restrict__ ws)
{
    const int blk  = blockIdx.x;
    const int ig   = blk & 15;
    const int head = (blk >> 4) & 3;
    const int b    = blk >> 6;
    const int i0   = ig * 16;
    const int tid  = threadIdx.x;
    const int lane = tid & 63;
    const int wid  = tid >> 6;
    const int quad = lane >> 4;
    const int l15  = lane & 15;
    const int bh   = b * H_ + head;

    __shared__ float    P_s[16 * 256];
    __shared__ ushort_t Pb_s[16 * 264];
    __shared__ float    ei_s[16 * 64];
    __shared__ float    si_s[16 * 64];
    __shared__ unsigned long long adjm_s[16 * 4];
    __shared__ float    hp_s[16 * 68];

    const float*    ei_f = ws;
    const ushort_t* ej_b = (const ushort_t*)(ws + S_);
    const ushort_t* Wh_b = ej_b + S_;
    ushort_t*       conc = (ushort_t*)(ws + 2 * (size_t)S_);
    const float*    wa_base = Wa1 + (size_t)head * 12288;   // 192*64

    {   // stage ei rows (16 x 64 f32)
        const int ii = tid >> 4, c = tid & 15;
        *(float4*)&ei_s[ii * 64 + c * 4] =
            *(const float4*)&ei_f[((size_t)(bh * 256 + i0 + ii)) * 64 + c * 4];
    }
    {   // adj bitmasks
        int av[16];
        #pragma unroll
        for (int r = 0; r < 16; ++r)
            av[r] = adj[((size_t)(b * 256 + i0 + r)) * 256 + tid];
        #pragma unroll
        for (int r = 0; r < 16; ++r) {
            unsigned long long mk = __ballot(av[r] != 0);
            if (lane == 0) adjm_s[r * 4 + wid] = mk;
        }
    }

    // ---- persistent per-wave registers (i-invariant) ----
    uint4   ejr[4][2];     // raw ej pairs, j = wid*64 + nt*16 + l15   [nt][ks]
    short8  afrWe[4][2];   // We^T frags, e = mt*16 + l15              [mt][ks]
    floatx4 sjaccT[4][4];  // sj^T[e][j]                               [mt][nt]
    float   w6[4][4], w4[4][4];  // 0.6*wa2[e], 0.4*wa2[e]
    #pragma unroll
    for (int nt = 0; nt < 4; ++nt) {
        const size_t jrow = (size_t)(bh * 256 + wid * 64 + nt * 16 + l15) * 64;
        #pragma unroll
        for (int kk = 0; kk < 2; ++kk)
            ejr[nt][kk] = *(const uint4*)&ej_b[jrow + kk * 32 + quad * 8];
    }
    #pragma unroll
    for (int mt = 0; mt < 4; ++mt) {
        #pragma unroll
        for (int ks = 0; ks < 2; ++ks)   // We = Wa1 rows 128..191: bw[e][k]=We[k][e]
            afrWe[mt][ks] = gcol<64>(wa_base + (size_t)(128 + ks * 32 + quad * 8) * 64
                                     + mt * 16 + l15);
        float4 wvv = *(const float4*)&wa2[head * 64 + mt * 16 + quad * 4];
        w6[mt][0] = 0.6f * wvv.x; w4[mt][0] = 0.4f * wvv.x;
        w6[mt][1] = 0.6f * wvv.y; w4[mt][1] = 0.4f * wvv.y;
        w6[mt][2] = 0.6f * wvv.z; w4[mt][2] = 0.4f * wvv.z;
        w6[mt][3] = 0.6f * wvv.w; w4[mt][3] = 0.4f * wvv.w;
    }
    {   // sjaccT = Wb^T (Wa1 rows 64..127) x Wh
        #pragma unroll
        for (int mt = 0; mt < 4; ++mt)
            #pragma unroll
            for (int nt = 0; nt < 4; ++nt) sjaccT[mt][nt] = (floatx4){0.f,0.f,0.f,0.f};
        #pragma unroll
        for (int ks = 2; ks < 4; ++ks) {
            short8 aWb[4], bWh[4];
            #pragma unroll
            for (int mt = 0; mt < 4; ++mt)
                aWb[mt] = gcol<64>(wa_base + (size_t)(64 + (ks - 2) * 32 + quad * 8) * 64
                                   + mt * 16 + l15);
            #pragma unroll
            for (int nt = 0; nt < 4; ++nt)
                bWh[nt] = *(const short8*)&Wh_b[((size_t)(bh * 256 + wid * 64 + nt * 16 + l15)) * 64
                                                + (ks - 2) * 32 + quad * 8];
            #pragma unroll
            for (int mt = 0; mt < 4; ++mt)
                #pragma unroll
                for (int nt = 0; nt < 4; ++nt)
                    sjaccT[mt][nt] = __builtin_amdgcn_mfma_f32_16x16x32_bf16(
                        aWb[mt], bWh[nt], sjaccT[mt][nt], 0, 0, 0);
        }
    }
    {   // si_s[i][e] = Wh[i0+i] @ Wa (rows 0..63) + ba1. C[m=i][n=e(wave e-range)]
        floatx4 siacc = (floatx4){0.f,0.f,0.f,0.f};
        #pragma unroll
        for (int ks = 0; ks < 2; ++ks) {
            short8 aWh = *(const short8*)&Wh_b[((size_t)(bh * 256 + i0 + l15)) * 64
                                               + ks * 32 + quad * 8];
            short8 bWa = gcol<64>(wa_base + (size_t)(ks * 32 + quad * 8) * 64
                                  + wid * 16 + l15);
            siacc = __builtin_amdgcn_mfma_f32_16x16x32_bf16(aWh, bWa, siacc, 0, 0, 0);
        }
        const float ba1v = ba1[head * 64 + wid * 16 + l15];
        #pragma unroll
        for (int reg = 0; reg < 4; ++reg)
            si_s[(quad * 4 + reg) * 64 + wid * 16 + l15] = siacc[reg] + ba1v;
    }
    const float ba2h = ba2[head];

    __syncthreads();   // ei_s / si_s / adjm_s ready

    // ==== barrier-free loop over 16 queries ====
    for (int i = 0; i < 16; ++i) {
        floatx4 acc[4][4];
        #pragma unroll
        for (int ks = 0; ks < 2; ++ks) {
            short8 tfr[4];
            float ev[8];
            *(float4*)&ev[0] = *(const float4*)&ei_s[i * 64 + ks * 32 + quad * 8];
            *(float4*)&ev[4] = *(const float4*)&ei_s[i * 64 + ks * 32 + quad * 8 + 4];
            #pragma unroll
            for (int nt = 0; nt < 4; ++nt) {
                const unsigned* rw = (const unsigned*)&ejr[nt][ks];
                union { unsigned u[4]; short8 s; } ow;
                #pragma unroll
                for (int p = 0; p < 4; ++p) {
                    float x0 = __uint_as_float(rw[p] << 16)         + ev[2 * p];
                    float x1 = __uint_as_float(rw[p] & 0xffff0000u) + ev[2 * p + 1];
                    ow.u[p] = pk2(lrelu(x0), lrelu(x1));
                }
                tfr[nt] = ow.s;
            }
            if (ks == 0) {
                #pragma unroll
                for (int mt = 0; mt < 4; ++mt)
                    #pragma unroll
                    for (int nt = 0; nt < 4; ++nt)
                        acc[mt][nt] = __builtin_amdgcn_mfma_f32_16x16x32_bf16(
                            afrWe[mt][0], tfr[nt], sjaccT[mt][nt], 0, 0, 0);
            } else {
                #pragma unroll
                for (int mt = 0; mt < 4; ++mt)
                    #pragma unroll
                    for (int nt = 0; nt < 4; ++nt)
                        acc[mt][nt] = __builtin_amdgcn_mfma_f32_16x16x32_bf16(
                            afrWe[mt][1], tfr[nt], acc[mt][nt], 0, 0, 0);
            }
        }

        // epilogue: logit[j] = sum_e lrelu(q^T[e][j]+si[e])*wa2[e] + ba2
        float sv[4][4];
        #pragma unroll
        for (int mt = 0; mt < 4; ++mt)
            *(float4*)&sv[mt][0] = *(const float4*)&si_s[i * 64 + mt * 16 + quad * 4];
        #pragma unroll
        for (int nt = 0; nt < 4; ++nt) {
            float val = 0.f;
            #pragma unroll
            for (int mt = 0; mt < 4; ++mt)
                #pragma unroll
                for (int reg = 0; reg < 4; ++reg) {
                    const float t = acc[mt][nt][reg] + sv[mt][reg];
                    val = fmaf(t, w6[mt][reg], val);
                    val = fmaf(fabsf(t), w4[mt][reg], val);
                }
            val += __shfl_xor(val, 16, 64);
            val += __shfl_xor(val, 32, 64);
            if (quad == 0)
                P_s[i * 256 + wid * 64 + nt * 16 + l15] = val + ba2h;
        }
    }
    __syncthreads();   // all logits published

    // ==== wave-local masked softmax: wave wid owns rows wid, wid+4, +8, +12 ====
    #pragma unroll
    for (int rr = 0; rr < 4; ++rr) {
        const int r = rr * 4 + wid;
        float4 v = *(const float4*)&P_s[r * 256 + lane * 4];
        const unsigned mk = (unsigned)(adjm_s[r * 4 + quad] >> (l15 * 4)) & 0xFu;
        float v0 = (mk & 1u) ? v.x : -1e9f;
        float v1 = (mk & 2u) ? v.y : -1e9f;
        float v2 = (mk & 4u) ? v.z : -1e9f;
        float v3 = (mk & 8u) ? v.w : -1e9f;
        float m = fmaxf(fmaxf(v0, v1), fmaxf(v2, v3));
        #pragma unroll
        for (int off = 32; off >= 1; off >>= 1) m = fmaxf(m, __shfl_xor(m, off, 64));
        float p0 = __expf(v0 - m), p1 = __expf(v1 - m);
        float p2 = __expf(v2 - m), p3 = __expf(v3 - m);
        float s = (p0 + p1) + (p2 + p3);
        #pragma unroll
        for (int off = 32; off >= 1; off >>= 1) s += __shfl_xor(s, off, 64);
        const float inv = 1.f / s;
        uint2 o; o.x = pk2(p0 * inv, p1 * inv); o.y = pk2(p2 * inv, p3 * inv);
        *(uint2*)&Pb_s[r * 264 + lane * 4] = o;
    }
    __syncthreads();   // Pb complete

    // ==== hp GEMM: M=16 (i), N=64 (d=wid*16+l15), K=256 (j); Wh gather ====
    floatx4 hacc = (floatx4){0.f,0.f,0.f,0.f};
    #pragma unroll
    for (int s = 0; s < 8; ++s) {
        short8 af = *(const short8*)&Pb_s[l15 * 264 + s * 32 + quad * 8];
        short8 bf;
        #pragma unroll
        for (int jj = 0; jj < 8; ++jj)
            bf[jj] = (short)Wh_b[((size_t)(bh * 256) + s * 32 + quad * 8 + jj) * 64 + wid * 16 + l15];
        hacc = __builtin_amdgcn_mfma_f32_16x16x32_bf16(af, bf, hacc, 0, 0, 0);
    }
    #pragma unroll
    for (int reg = 0; reg < 4; ++reg)
        hp_s[(quad * 4 + reg) * 68 + wid * 16 + l15] = hacc[reg];
    __syncthreads();

    // ==== per-row LN over 64 d -> conc (bf16) ====
    const float gg = ln_g[head * 64 + lane];
    const float bb = ln_b[head * 64 + lane];
    #pragma unroll
    for (int pss = 0; pss < 4; ++pss) {
        const int r = pss * 4 + wid;
        const float v = hp_s[r * 68 + lane];
        float s1 = v, s2 = v * v;
        #pragma unroll
        for (int off = 32; off >= 1; off >>= 1) {
            s1 += __shfl_xor(s1, off, 64);
            s2 += __shfl_xor(s2, off, 64);
        }
        const float mean = s1 * (1.f / 64.f);
        const float var = s2 * (1.f / 64.f) - mean * mean;
        const float o = (v - mean) * __frsqrt_rn(var + EPS_) * gg + bb;
        conc[((size_t)(b * 256 + i0 + r)) * 256 + head * 64 + lane] = f2b(o);
    }
}

// ---------------------------------------------------------------------------
// out2: grid 256 (8 rows/block). Wo fragments gathered directly from f32 Wo
// (stride-256 columns, coalesced across l15). A rows 8-15 dup 0-7; quad>=2
// lanes skip LN/stores.
// ---------------------------------------------------------------------------
__global__ __launch_bounds__(256) void out2_kernel(
    const float* __restrict__ h, const float* __restrict__ Wo,
    const float* __restrict__ bo, const float* __restrict__ ln2_g,
    const float* __restrict__ ln2_b, const ushort_t* __restrict__ conc,
    float* __restrict__ out)
{
    const int rowbase = blockIdx.x * 8;
    const int tid = threadIdx.x, lane = tid & 63, wid = tid >> 6;
    const int quad = lane >> 4, l15 = lane & 15;

    __shared__ float s1a[8][4], s2a[8][4];

    floatx4 acc[4];
    #pragma unroll
    for (int nt = 0; nt < 4; ++nt) acc[nt] = (floatx4){0.f,0.f,0.f,0.f};

    #pragma unroll 2
    for (int ks = 0; ks < 8; ++ks) {
        short8 afr = *(const short8*)&conc[(size_t)(rowbase + (l15 & 7)) * 256 + ks * 32 + quad * 8];
        #pragma unroll
        for (int nt = 0; nt < 4; ++nt) {
            // B[o][f contiguous 8] = Wo[f][o]: stride-256 gather
            short8 bfr = gcol<256>(Wo + (size_t)(ks * 32 + quad * 8) * 256
                                   + wid * 64 + nt * 16 + l15);
            acc[nt] = __builtin_amdgcn_mfma_f32_16x16x32_bf16(afr, bfr, acc[nt], 0, 0, 0);
        }
    }

    float x[4][4];
    if (quad < 2) {
        float s1[4], s2[4];
        #pragma unroll
        for (int reg = 0; reg < 4; ++reg) { s1[reg] = 0.f; s2[reg] = 0.f; }
        #pragma unroll
        for (int nt = 0; nt < 4; ++nt) {
            const int col = wid * 64 + nt * 16 + l15;
            const float bv = bo[col];
            #pragma unroll
            for (int reg = 0; reg < 4; ++reg) {
                const int row = rowbase + quad * 4 + reg;
                float v = acc[nt][reg] + bv + h[(size_t)row * 256 + col];
                x[nt][reg] = v;
                s1[reg] += v;
                s2[reg] += v * v;
            }
        }
        #pragma unroll
        for (int reg = 0; reg < 4; ++reg) {
            #pragma unroll
            for (int off = 1; off <= 8; off <<= 1) {
                s1[reg] += __shfl_xor(s1[reg], off, 64);
                s2[reg] += __shfl_xor(s2[reg], off, 64);
            }
            if (l15 == 0) {
                s1a[quad * 4 + reg][wid] = s1[reg];
                s2a[quad * 4 + reg][wid] = s2[reg];
            }
        }
    }
    __syncthreads();

    if (quad < 2) {
        #pragma unroll
        for (int reg = 0; reg < 4; ++reg) {
            const int r = quad * 4 + reg;
            const float S1 = s1a[r][0] + s1a[r][1] + s1a[r][2] + s1a[r][3];
            const float S2 = s2a[r][0] + s2a[r][1] + s2a[r][2] + s2a[r][3];
            const float mean = S1 * (1.f / 256.f);
            const float var = S2 * (1.f / 256.f) - mean * mean;
            const float rs = __frsqrt_rn(var + EPS_);
            const int row = rowbase + r;
            #pragma unroll
            for (int nt = 0; nt < 4; ++nt) {
                const int col = wid * 64 + nt * 16 + l15;
                out[(size_t)row * 256 + col] =
                    (x[nt][reg] - mean) * rs * ln2_g[col] + ln2_b[col];
            }
        }
    }
}

// ---------------------------------------------------------------------------
extern "C" void kernel_launch(void* const* d_in, const int* in_sizes, int n_in,
                              void* d_out, int out_size, void* d_ws, size_t ws_size,
                              hipStream_t stream)
{
    const float* h    = (const float*)d_in[0];
    const int*   adj  = (const int*)  d_in[1];
    const float* W    = (const float*)d_in[2];
    const float* We1  = (const float*)d_in[3];
    const float* be1  = (const float*)d_in[4];
    const float* Wa1  = (const float*)d_in[5];
    const float* ba1  = (const float*)d_in[6];
    const float* wa2  = (const float*)d_in[7];
    const float* ba2  = (const float*)d_in[8];
    const float* ln_g = (const float*)d_in[9];
    const float* ln_b = (const float*)d_in[10];
    const float* Wo   = (const float*)d_in[11];
    const float* bo   = (const float*)d_in[12];
    const float* ln2g = (const float*)d_in[13];
    const float* ln2b = (const float*)d_in[14];

    float* ws = (float*)d_ws;
    ushort_t* conc = (ushort_t*)(ws + 2 * (size_t)S_);
    float* out = (float*)d_out;

    prep2_kernel<<<768, 256, 0, stream>>>(h, W, We1, be1, ws);
    attn_kernel <<<512, 256, 0, stream>>>(adj, Wa1, ba1, wa2, ba2, ln_g, ln_b, ws);
    out2_kernel <<<256, 256, 0, stream>>>(h, Wo, bo, ln2g, ln2b, conc, out);
}